// Round 6
// baseline (328.815 us; speedup 1.0000x reference)
//
#include <hip/hip_runtime.h>
#include <math.h>

namespace {
constexpr int R_RUNS   = 4096;
constexpr int T_STEPS  = 2048;
constexpr int K_CHUNKS = 64;                 // chunks per run
constexpr int L_CHUNK  = 32;                 // timesteps per chunk
constexpr int PAD_T    = 33;                 // tile row stride: write (lane+j)%32 2-way,
                                             // read 2-halves 2-way -> conflict-free
}

__device__ __forceinline__ float sigmoidf_(float x) {
    return 1.0f / (1.0f + expf(-x));
}

__device__ __forceinline__ float dot8u(const float* __restrict__ p, const float m[8]) {
    // p is wave-uniform (SGPR base + imm) -> s_load; operands SGPR x VGPR
    float s = p[0] * m[0];
    s = fmaf(p[1], m[1], s);
    s = fmaf(p[2], m[2], s);
    s = fmaf(p[3], m[3], s);
    s = fmaf(p[4], m[4], s);
    s = fmaf(p[5], m[5], s);
    s = fmaf(p[6], m[6], s);
    s = fmaf(p[7], m[7], s);
    return s;
}

// ---------------------------------------------------------------------------
// Single fused kernel. Wave <- ticket t: k = t>>6 (chunk), g = t&63 (run grp).
// Ticket order guarantees all predecessors (same g, k'<k) started earlier
// => decoupled lookback cannot deadlock, residency not required.
//
// Phase 1: bv[j] = b_{t0-1+j} (recurrence inputs), sxz[j] = x.eta + z.zeta,
//          all via wave-uniform scalar loads; chunk summary u -> U[k][r];
//          publish bit k of mask[g] (fence + atomicOr).
// Lookback: poll mask[g] until bits 0..k-1 set; masked unrolled scan of U.
// Phase 3: register-only recurrence replay, LDS tile, coalesced flush.
// ---------------------------------------------------------------------------
extern "C" __global__ __launch_bounds__(256, 4)
void dlm_one(const float* __restrict__ Xt, const float* __restrict__ Zt,
             const float* __restrict__ G, const float* __restrict__ eta,
             const float* __restrict__ zeta, const float* __restrict__ gamma,
             float* __restrict__ U, unsigned long long* __restrict__ mask,
             unsigned int* __restrict__ ticket, float* __restrict__ out)
{
    __shared__ float tile[4][64][PAD_T];

    const int tid  = threadIdx.x;
    const int wid  = tid >> 6;
    const int lane = tid & 63;

    int tk = 0;
    if (lane == 0) tk = (int)atomicAdd(ticket, 1u);
    tk = __builtin_amdgcn_readfirstlane(tk);
    const int k  = tk >> 6;            // 0..63  (scalar)
    const int g  = tk & 63;            // 0..63  (scalar)
    const int r  = (g << 6) + lane;
    const int t0 = k * L_CHUNK;

    // ---- per-run params
    const float4 g0 = *reinterpret_cast<const float4*>(gamma + (size_t)r * 8);
    const float4 g1 = *reinterpret_cast<const float4*>(gamma + (size_t)r * 8 + 4);
    const float4 e0 = *reinterpret_cast<const float4*>(eta   + (size_t)r * 8);
    const float4 e1 = *reinterpret_cast<const float4*>(eta   + (size_t)r * 8 + 4);
    const float4 z0 = *reinterpret_cast<const float4*>(zeta  + (size_t)r * 8);
    const float4 z1 = *reinterpret_cast<const float4*>(zeta  + (size_t)r * 8 + 4);
    const float gm[8] = {g0.x, g0.y, g0.z, g0.w, g1.x, g1.y, g1.z, g1.w};
    const float et[8] = {e0.x, e0.y, e0.z, e0.w, e1.x, e1.y, e1.z, e1.w};
    const float zz[8] = {z0.x, z0.y, z0.z, z0.w, z1.x, z1.y, z1.z, z1.w};
    const float gh = sigmoidf_(G[r]);

    // ---- phase 1: scalar-load sweep over x/z rows of this chunk
    const float* __restrict__ zbase = Zt + (size_t)t0 * 8;   // uniform
    const float* __restrict__ xbase = Xt + (size_t)t0 * 8;   // uniform

    float bv[L_CHUNK];    // b_{t0-1+j}
    float sxz[L_CHUNK];   // x_{t0+j}.eta + z_{t0+j}.zeta
    bv[0] = (k > 0) ? dot8u(zbase - 8, gm) : 0.0f;
    #pragma unroll
    for (int j = 0; j < L_CHUNK; ++j) {
        const float* __restrict__ zr = zbase + j * 8;
        const float* __restrict__ xr = xbase + j * 8;
        sxz[j] = dot8u(xr, et) + dot8u(zr, zz);
        if (j < L_CHUNK - 1) bv[j + 1] = dot8u(zr, gm);
    }

    float u = 0.0f;
    #pragma unroll
    for (int j = 0; j < L_CHUNK; ++j) u = fmaf(gh, u, bv[j]);
    U[(size_t)k * R_RUNS + r] = u;
    __threadfence();                                   // release U before flag
    if (lane == 0) atomicOr(&mask[g], 1ull << k);

    // ---- A = gh^32
    float A = gh;
    #pragma unroll
    for (int i = 0; i < 5; ++i) A = A * A;

    // ---- lookback: wait for bits 0..k-1, then masked unrolled scan
    float theta = 0.0f;
    if (k > 0) {
        const unsigned long long need = (1ull << k) - 1ull;
        while ((__hip_atomic_load(&mask[g], __ATOMIC_ACQUIRE,
                                  __HIP_MEMORY_SCOPE_AGENT) & need) != need) {
            __builtin_amdgcn_s_sleep(1);
        }
        __threadfence();                               // acquire side

        #pragma unroll
        for (int base = 0; base < K_CHUNKS; base += 8) {
            if (base < k) {                            // uniform branch
                float v[8];
                #pragma unroll
                for (int i = 0; i < 8; ++i)
                    v[i] = U[(size_t)(base + i) * R_RUNS + r];  // always in-bounds
                #pragma unroll
                for (int i = 0; i < 8; ++i) {
                    const bool act = (base + i) < k;
                    theta = fmaf(act ? A : 1.0f, theta, act ? v[i] : 0.0f);
                }
            }
        }
    }

    // ---- phase 3: register-only replay -> LDS tile
    #pragma unroll
    for (int j = 0; j < L_CHUNK; ++j) {
        theta = fmaf(gh, theta, bv[j]);
        tile[wid][lane][j] = theta + sxz[j];
    }

    // ---- flush (wave-private tile): 2 rows x 128B contiguous per instr
    const int rrh = lane >> 5;
    const int c   = lane & 31;
    #pragma unroll
    for (int it = 0; it < 32; ++it) {
        const int rr = it * 2 + rrh;
        out[(size_t)((g << 6) + rr) * T_STEPS + t0 + c] = tile[wid][rr][c];
    }
}

// ---------------------------------------------------------------------------
extern "C" void kernel_launch(void* const* d_in, const int* in_sizes, int n_in,
                              void* d_out, int out_size, void* d_ws, size_t ws_size,
                              hipStream_t stream)
{
    const float* Xt    = (const float*)d_in[0];
    const float* Zt    = (const float*)d_in[1];
    const float* G     = (const float*)d_in[2];
    const float* eta   = (const float*)d_in[3];
    const float* zeta  = (const float*)d_in[4];
    const float* gamma = (const float*)d_in[5];
    float* out = (float*)d_out;

    // ws layout: U[64][4096] (1 MB) | mask[64] (512B) | ticket (4B)
    char* ws = (char*)d_ws;
    float* U = (float*)ws;
    unsigned long long* mask = (unsigned long long*)(ws + (size_t)K_CHUNKS * R_RUNS * 4);
    unsigned int* ticket = (unsigned int*)(ws + (size_t)K_CHUNKS * R_RUNS * 4 + 64 * 8);

    // zero mask + ticket each launch (captured in the graph, replays each time)
    hipMemsetAsync(mask, 0, 64 * 8 + 16, stream);

    const dim3 blk(256);
    const dim3 grid(K_CHUNKS * 64 / 4);       // 1024 blocks = 4096 waves
    dlm_one<<<grid, blk, 0, stream>>>(Xt, Zt, G, eta, zeta, gamma, U, mask, ticket, out);
}

// Round 7
// 26.209 us; speedup vs baseline: 12.5459x; 12.5459x over previous
//
#include <hip/hip_runtime.h>
#include <math.h>

namespace {
constexpr int R_RUNS   = 4096;
constexpr int T_STEPS  = 2048;
constexpr int K_CHUNKS = 64;                 // chunks per run
constexpr int L_CHUNK  = 32;                 // timesteps per chunk
constexpr int NG       = 64;                 // run groups (64 runs each)
constexpr int PAD_T    = 33;                 // tile row stride (conflict-free write/read)
}

__device__ __forceinline__ float sigmoidf_(float x) {
    return 1.0f / (1.0f + expf(-x));
}

__device__ __forceinline__ float dot8u(const float* __restrict__ p, const float m[8]) {
    // p wave-uniform -> scalar loads
    float s = p[0] * m[0];
    s = fmaf(p[1], m[1], s);
    s = fmaf(p[2], m[2], s);
    s = fmaf(p[3], m[3], s);
    s = fmaf(p[4], m[4], s);
    s = fmaf(p[5], m[5], s);
    s = fmaf(p[6], m[6], s);
    s = fmaf(p[7], m[7], s);
    return s;
}

// ---------------------------------------------------------------------------
// K1: chunk summaries U[k][r].
// Fast path (gh uniform within the wave's 64 runs, true for this input):
//   u_k[r] = gamma_r . S   with  S = sum_j gh^{31-j} z_{t0-1+j}  (8-vector).
//   Lane j<32 loads one z row, weights it, 48-shfl tree reduce, 8 fma/lane.
// Fallback: R2's per-lane serial sweep with wave-uniform scalar z loads.
// ---------------------------------------------------------------------------
extern "C" __global__ __launch_bounds__(256, 4)
void dlm_k1_summary(const float* __restrict__ Zt, const float* __restrict__ G,
                    const float* __restrict__ gamma, float* __restrict__ U)
{
    const int tid  = threadIdx.x;
    const int wid  = __builtin_amdgcn_readfirstlane((int)(tid >> 6));
    const int lane = tid & 63;
    const int wave = blockIdx.x * 4 + wid;
    const int g    = wave & (NG - 1);
    const int k    = wave >> 6;
    const int r    = (g << 6) + lane;
    const int t0   = k * L_CHUNK;

    const float4 g0 = *reinterpret_cast<const float4*>(gamma + (size_t)r * 8);
    const float4 g1 = *reinterpret_cast<const float4*>(gamma + (size_t)r * 8 + 4);
    const float gm[8] = {g0.x, g0.y, g0.z, g0.w, g1.x, g1.y, g1.z, g1.w};

    const float gr  = G[r];
    const float gr0 = __builtin_amdgcn_readfirstlane(gr);
    const bool uni  = (__ballot(gr == gr0) == ~0ull);

    if (uni) {
        const float gh = sigmoidf_(gr0);              // scalar
        // lane j<32 holds weighted z row t0-1+j
        float c[8] = {0.f, 0.f, 0.f, 0.f, 0.f, 0.f, 0.f, 0.f};
        const bool active = (lane < 32) && !(k == 0 && lane == 0);
        if (active) {
            const float* __restrict__ zr = Zt + (size_t)(t0 - 1 + lane) * 8;
            const float4 a = *reinterpret_cast<const float4*>(zr);
            const float4 b = *reinterpret_cast<const float4*>(zr + 4);
            // w = gh^(31-lane), exact binary exponentiation
            int e = 31 - lane;
            float w = 1.0f, p = gh;
            #pragma unroll
            for (int i = 0; i < 5; ++i) {
                if (e & 1) w *= p;
                p *= p;
                e >>= 1;
            }
            c[0] = a.x * w; c[1] = a.y * w; c[2] = a.z * w; c[3] = a.w * w;
            c[4] = b.x * w; c[5] = b.y * w; c[6] = b.z * w; c[7] = b.w * w;
        }
        // tree-reduce across 64 lanes (upper half zeros)
        #pragma unroll
        for (int m = 1; m < 64; m <<= 1) {
            #pragma unroll
            for (int i = 0; i < 8; ++i)
                c[i] += __shfl_xor(c[i], m, 64);
        }
        // u = gamma_r . S
        float u = c[0] * gm[0];
        #pragma unroll
        for (int i = 1; i < 8; ++i) u = fmaf(c[i], gm[i], u);
        U[(size_t)k * R_RUNS + r] = u;
    } else {
        // fallback: R2 path (wave-uniform scalar z loads)
        const float gh = sigmoidf_(gr);
        const float* __restrict__ zbase = Zt + (size_t)t0 * 8;
        float b_prev = (k > 0) ? dot8u(zbase - 8, gm) : 0.0f;
        float u = 0.0f;
        #pragma unroll
        for (int j = 0; j < L_CHUNK; ++j) {
            u = fmaf(gh, u, b_prev);
            b_prev = dot8u(zbase + j * 8, gm);
        }
        U[(size_t)k * R_RUNS + r] = u;
    }
}

// ---------------------------------------------------------------------------
// K3: batched masked U-scan for theta-start, then replay chunk with output
// math (wave-uniform scalar x/z loads), stage in wave-private LDS tile,
// coalesced flush (no block barrier needed).
// ---------------------------------------------------------------------------
extern "C" __global__ __launch_bounds__(256, 4)
void dlm_k3_output(const float* __restrict__ Xt, const float* __restrict__ Zt,
                   const float* __restrict__ G, const float* __restrict__ eta,
                   const float* __restrict__ zeta, const float* __restrict__ gamma,
                   const float* __restrict__ U, float* __restrict__ out)
{
    __shared__ float tile[4][64][PAD_T];

    const int tid  = threadIdx.x;
    const int wid  = __builtin_amdgcn_readfirstlane((int)(tid >> 6));
    const int lane = tid & 63;
    const int wave = blockIdx.x * 4 + wid;
    const int g    = wave & (NG - 1);
    const int k    = wave >> 6;
    const int r    = (g << 6) + lane;
    const int t0   = k * L_CHUNK;

    const float4 g0 = *reinterpret_cast<const float4*>(gamma + (size_t)r * 8);
    const float4 g1 = *reinterpret_cast<const float4*>(gamma + (size_t)r * 8 + 4);
    const float4 e0 = *reinterpret_cast<const float4*>(eta   + (size_t)r * 8);
    const float4 e1 = *reinterpret_cast<const float4*>(eta   + (size_t)r * 8 + 4);
    const float4 z0 = *reinterpret_cast<const float4*>(zeta  + (size_t)r * 8);
    const float4 z1 = *reinterpret_cast<const float4*>(zeta  + (size_t)r * 8 + 4);
    const float gm[8] = {g0.x, g0.y, g0.z, g0.w, g1.x, g1.y, g1.z, g1.w};
    const float et[8] = {e0.x, e0.y, e0.z, e0.w, e1.x, e1.y, e1.z, e1.w};
    const float zz[8] = {z0.x, z0.y, z0.z, z0.w, z1.x, z1.y, z1.z, z1.w};
    const float gh = sigmoidf_(G[r]);

    // ---- A = gh^32
    float A = gh;
    #pragma unroll
    for (int i = 0; i < 5; ++i) A = A * A;

    // ---- theta at t0-1: batched masked scan over U[0..k-1][r]
    float theta = 0.0f;
    #pragma unroll
    for (int base = 0; base < K_CHUNKS; base += 8) {
        if (base < k) {                          // wave-uniform branch
            float v[8];
            #pragma unroll
            for (int i = 0; i < 8; ++i)
                v[i] = U[(size_t)(base + i) * R_RUNS + r];   // in-bounds (<=63)
            #pragma unroll
            for (int i = 0; i < 8; ++i) {
                const bool act = (base + i) < k;
                theta = fmaf(act ? A : 1.0f, theta, act ? v[i] : 0.0f);
            }
        }
    }

    // ---- replay chunk with output math (x/z via wave-uniform scalar loads)
    const float* __restrict__ zbase = Zt + (size_t)t0 * 8;
    const float* __restrict__ xbase = Xt + (size_t)t0 * 8;
    float b_prev = (k > 0) ? dot8u(zbase - 8, gm) : 0.0f;

    #pragma unroll
    for (int j = 0; j < L_CHUNK; ++j) {
        const float* __restrict__ zr = zbase + j * 8;
        const float* __restrict__ xr = xbase + j * 8;
        float bx = xr[0] * et[0], bz = zr[0] * zz[0], bn = zr[0] * gm[0];
        #pragma unroll
        for (int q = 1; q < 8; ++q) {
            bx = fmaf(xr[q], et[q], bx);
            bz = fmaf(zr[q], zz[q], bz);
            bn = fmaf(zr[q], gm[q], bn);
        }
        theta = fmaf(gh, theta, b_prev);
        b_prev = bn;
        tile[wid][lane][j] = theta + bx + bz;
    }

    // ---- flush (wave-private tile; intra-wave LDS ordering suffices)
    const int rrh = lane >> 5;
    const int c   = lane & 31;
    #pragma unroll
    for (int it = 0; it < 32; ++it) {
        const int rr = it * 2 + rrh;
        out[(size_t)((g << 6) + rr) * T_STEPS + t0 + c] = tile[wid][rr][c];
    }
}

// ---------------------------------------------------------------------------
extern "C" void kernel_launch(void* const* d_in, const int* in_sizes, int n_in,
                              void* d_out, int out_size, void* d_ws, size_t ws_size,
                              hipStream_t stream)
{
    const float* Xt    = (const float*)d_in[0];
    const float* Zt    = (const float*)d_in[1];
    const float* G     = (const float*)d_in[2];
    const float* eta   = (const float*)d_in[3];
    const float* zeta  = (const float*)d_in[4];
    const float* gamma = (const float*)d_in[5];
    float* out = (float*)d_out;

    float* U = (float*)d_ws;                  // U[64][4096], 1 MB

    const dim3 blk(256);
    const dim3 grid(NG * K_CHUNKS / 4);       // 1024 blocks (4 waves each)

    dlm_k1_summary<<<grid, blk, 0, stream>>>(Zt, G, gamma, U);
    dlm_k3_output <<<grid, blk, 0, stream>>>(Xt, Zt, G, eta, zeta, gamma, U, out);
}